// Round 1
// baseline (11896.407 us; speedup 1.0000x reference)
//
#include <hip/hip_runtime.h>

#define T_STEPS 256
#define NBATCH  256
#define HID     1024

typedef short bf16x8 __attribute__((ext_vector_type(8)));
typedef float f32x4  __attribute__((ext_vector_type(4)));

__device__ inline short cvt_bf16(float f) {
  unsigned u = __builtin_bit_cast(unsigned, f);
  u += 0x7fffu + ((u >> 16) & 1u);   // round-to-nearest-even
  return (short)(u >> 16);
}

__device__ inline float fast_sigmoid(float x) {
  return __builtin_amdgcn_rcpf(1.0f + __builtin_amdgcn_exp2f(-1.44269504f * x));
}
__device__ inline float fast_tanh(float x) {
  return 2.0f * __builtin_amdgcn_rcpf(1.0f + __builtin_amdgcn_exp2f(-2.88539008f * x)) - 1.0f;
}

// ---------------- K1: cast fp32 -> bf16 (W_hh, W_fc, c_vector->h carry) ----
__global__ void cast_kernel(const float* __restrict__ Whh,
                            const float* __restrict__ Wfc,
                            const float* __restrict__ cvec,
                            short* __restrict__ Whhb,
                            short* __restrict__ Wfcb,
                            short* __restrict__ hb0) {
  long i = (long)blockIdx.x * blockDim.x + threadIdx.x;   // float4 quad index
  const long nWhh = 4L * HID * HID / 4;   // 1048576
  const long nWfc = 1L * HID * HID / 4;   // 262144
  const long nCv  = (long)NBATCH * HID / 4; // 65536
  const float4* src; short* dst; long q;
  if (i < nWhh)                  { src = (const float4*)Whh;  dst = Whhb; q = i; }
  else if (i < nWhh + nWfc)      { src = (const float4*)Wfc;  dst = Wfcb; q = i - nWhh; }
  else if (i < nWhh + nWfc + nCv){ src = (const float4*)cvec; dst = hb0;  q = i - nWhh - nWfc; }
  else return;
  float4 v = src[q];
  short4 o;
  o.x = cvt_bf16(v.x); o.y = cvt_bf16(v.y); o.z = cvt_bf16(v.z); o.w = cvt_bf16(v.w);
  *(short4*)(dst + q * 4) = o;
}

// ---------------- K2: b0 = b_ih+b_hh ; bc = b0 + W_ih @ b_fc (fp32) --------
__global__ void bias_kernel(const float* __restrict__ W_ih,
                            const float* __restrict__ b_ih,
                            const float* __restrict__ b_hh,
                            const float* __restrict__ b_fc,
                            float* __restrict__ b0, float* __restrict__ bc) {
  int w = threadIdx.x >> 6, l = threadIdx.x & 63;
  int n = blockIdx.x * 4 + w;          // 4096 rows, 4 waves/block
  const float* row = W_ih + (long)n * HID;
  float s = 0.f;
  for (int i = l; i < HID; i += 64) s += row[i] * b_fc[i];
  #pragma unroll
  for (int off = 32; off; off >>= 1) s += __shfl_xor(s, off, 64);
  if (l == 0) {
    float base = b_ih[n] + b_hh[n];
    b0[n] = base;
    bc[n] = base + s;
  }
}

// ---------------- K3: Wc[n,k] = sum_j W_ih[n,j] * W_fc[j,k]  (bf16 out) ----
__global__ void wc_kernel(const float* __restrict__ W_ih,
                          const float* __restrict__ W_fc,
                          short* __restrict__ Wc) {
  int w = threadIdx.x >> 6, l = threadIdx.x & 63;
  int tile = blockIdx.x * 4 + w;       // 16384 tiles: 256 n-tiles x 64 k-tiles
  int nt = tile >> 6, kt = tile & 63;
  int lr = l & 15, lq = l >> 4;
  f32x4 acc = {0.f, 0.f, 0.f, 0.f};
  const float* arow = W_ih + (long)(nt * 16 + lr) * HID + lq * 8;
  const float* bcol = W_fc + (long)(lq * 8) * HID + kt * 16 + lr;
  for (int jc = 0; jc < HID; jc += 32) {
    float4 a0 = *(const float4*)(arow + jc);
    float4 a1 = *(const float4*)(arow + jc + 4);
    bf16x8 a;
    a[0]=cvt_bf16(a0.x); a[1]=cvt_bf16(a0.y); a[2]=cvt_bf16(a0.z); a[3]=cvt_bf16(a0.w);
    a[4]=cvt_bf16(a1.x); a[5]=cvt_bf16(a1.y); a[6]=cvt_bf16(a1.z); a[7]=cvt_bf16(a1.w);
    bf16x8 b;
    #pragma unroll
    for (int jj = 0; jj < 8; ++jj) b[jj] = cvt_bf16(bcol[(long)(jc + jj) * HID]);
    acc = __builtin_amdgcn_mfma_f32_16x16x32_bf16(a, b, acc, 0, 0, 0);
  }
  int n = nt * 16 + lq * 4, k = kt * 16 + lr;
  #pragma unroll
  for (int r = 0; r < 4; ++r) Wc[(long)(n + r) * HID + k] = cvt_bf16(acc[r]);
}

// ---------------- per-step: gates GEMM (split-K over 2 waves) + LSTM cell --
__global__ void step_kernel(int t, int use_c,
                            const short* __restrict__ xc, long xc_rs,
                            const short* __restrict__ xh,
                            const short* __restrict__ Wc,
                            const short* __restrict__ Whh,
                            const float* __restrict__ bias,
                            const float* __restrict__ cprev, long cprev_rs,
                            float* __restrict__ hst, float* __restrict__ cst,
                            short* __restrict__ hb_next,
                            short* __restrict__ cb_next, long cbn_rs) {
  int w = threadIdx.x >> 6, l = threadIdx.x & 63;
  int tile = blockIdx.x;               // 1024 tiles: 16 m-tiles x 64 u-tiles
  int mt = tile >> 6, ut = tile & 63;
  int lr = l & 15, lq = l >> 4;
  __shared__ float lds[4][16][16];
  f32x4 acc[4] = {};
  if (w || use_c) {
    const short* X  = w ? xh : xc;
    long xrs        = w ? (long)HID : xc_rs;
    const short* Wt = w ? Whh : Wc;
    const short* xrow = X  + (long)(mt * 16 + lr) * xrs + lq * 8;
    const short* wrow = Wt + (long)(ut * 16 + lr) * HID + lq * 8;
    #pragma unroll 4
    for (int kc = 0; kc < HID; kc += 32) {
      bf16x8 a = *(const bf16x8*)(xrow + kc);
      #pragma unroll
      for (int g = 0; g < 4; ++g) {
        bf16x8 b = *(const bf16x8*)(wrow + (long)g * HID * HID + kc);
        acc[g] = __builtin_amdgcn_mfma_f32_16x16x32_bf16(a, b, acc[g], 0, 0, 0);
      }
    }
  }
  if (w) {
    #pragma unroll
    for (int g = 0; g < 4; ++g)
      #pragma unroll
      for (int r = 0; r < 4; ++r)
        lds[g][lq * 4 + r][lr] = acc[g][r];
  }
  __syncthreads();
  if (!w) {
    int u = ut * 16 + lr;
    float bi[4];
    #pragma unroll
    for (int g = 0; g < 4; ++g) bi[g] = bias[g * HID + u];
    #pragma unroll
    for (int r = 0; r < 4; ++r) {
      int row = lq * 4 + r;
      int m = mt * 16 + row;
      float xi = acc[0][r] + lds[0][row][lr] + bi[0];
      float xf = acc[1][r] + lds[1][row][lr] + bi[1];
      float xg = acc[2][r] + lds[2][row][lr] + bi[2];
      float xo = acc[3][r] + lds[3][row][lr] + bi[3];
      float c_old = cprev[(long)m * cprev_rs + u];
      float ig = fast_sigmoid(xi), fg = fast_sigmoid(xf);
      float gg = fast_tanh(xg),   og = fast_sigmoid(xo);
      float cn = fg * c_old + ig * gg;
      float hn = og * fast_tanh(cn);
      long o = ((long)m * T_STEPS + t) * HID + u;
      hst[o] = hn;
      cst[o] = cn;
      hb_next[(long)m * HID + u]   = cvt_bf16(hn);
      cb_next[(long)m * cbn_rs + u] = cvt_bf16(cn);
    }
  }
}

// ---------------- K4: outputs = c_states @ W_fc.T + b_fc  ------------------
__device__ inline bf16x8 load_frag(const short* p) { return *(const bf16x8*)p; }
__device__ inline bf16x8 load_frag(const float* p) {
  float4 v0 = *(const float4*)p;
  float4 v1 = *(const float4*)(p + 4);
  bf16x8 r;
  r[0]=cvt_bf16(v0.x); r[1]=cvt_bf16(v0.y); r[2]=cvt_bf16(v0.z); r[3]=cvt_bf16(v0.w);
  r[4]=cvt_bf16(v1.x); r[5]=cvt_bf16(v1.y); r[6]=cvt_bf16(v1.z); r[7]=cvt_bf16(v1.w);
  return r;
}

template <typename AT>
__global__ void fc_kernel(const AT* __restrict__ A,      // [65536,1024] rows = b*256+t
                          const short* __restrict__ Bw,  // W_fc bf16 [1024,1024]
                          const float* __restrict__ b_fc,
                          float* __restrict__ out) {
  int w = threadIdx.x >> 6, l = threadIdx.x & 63;
  int wave = blockIdx.x * 4 + w;       // 16384 waves: 1024 m-tiles x 16 u-tiles
  int ut = wave & 15, mt = wave >> 4;
  int lr = l & 15, lq = l >> 4;
  f32x4 acc[4][4] = {};
  const AT* arow[4]; const short* brow[4];
  #pragma unroll
  for (int i = 0; i < 4; ++i) {
    arow[i] = A  + (long)(mt * 64 + i * 16 + lr) * HID + lq * 8;
    brow[i] = Bw + (long)(ut * 64 + i * 16 + lr) * HID + lq * 8;
  }
  for (int kc = 0; kc < HID; kc += 32) {
    bf16x8 a[4], b[4];
    #pragma unroll
    for (int i = 0; i < 4; ++i) {
      a[i] = load_frag(arow[i] + kc);
      b[i] = *(const bf16x8*)(brow[i] + kc);
    }
    #pragma unroll
    for (int mi = 0; mi < 4; ++mi)
      #pragma unroll
      for (int ui = 0; ui < 4; ++ui)
        acc[mi][ui] = __builtin_amdgcn_mfma_f32_16x16x32_bf16(a[mi], b[ui], acc[mi][ui], 0, 0, 0);
  }
  int u0 = ut * 64;
  #pragma unroll
  for (int ui = 0; ui < 4; ++ui) {
    float bf = b_fc[u0 + ui * 16 + lr];
    #pragma unroll
    for (int mi = 0; mi < 4; ++mi)
      #pragma unroll
      for (int r = 0; r < 4; ++r) {
        long mo = (long)mt * 64 + mi * 16 + lq * 4 + r;
        out[mo * HID + u0 + ui * 16 + lr] = acc[mi][ui][r] + bf;
      }
  }
}

// ---------------------------------------------------------------------------
extern "C" void kernel_launch(void* const* d_in, const int* in_sizes, int n_in,
                              void* d_out, int out_size, void* d_ws, size_t ws_size,
                              hipStream_t stream) {
  const float* cvec = (const float*)d_in[0];
  const float* W_ih = (const float*)d_in[1];
  const float* W_hh = (const float*)d_in[2];
  const float* b_ih = (const float*)d_in[3];
  const float* b_hh = (const float*)d_in[4];
  const float* W_fc = (const float*)d_in[5];
  const float* b_fc = (const float*)d_in[6];
  float* out = (float*)d_out;
  float* hst = out;
  float* cst = out + (long)NBATCH * T_STEPS * HID;
  float* ost = out + 2L * NBATCH * T_STEPS * HID;

  char* base = (char*)d_ws;
  size_t off = 0;
  auto carve = [&](size_t bytes) -> char* {
    char* r = base + off;
    off = (off + bytes + 255) & ~(size_t)255;
    return r;
  };
  short* Wc   = (short*)carve(4L * HID * HID * 2);   // 8 MB
  short* Whhb = (short*)carve(4L * HID * HID * 2);   // 8 MB
  short* Wfcb = (short*)carve(1L * HID * HID * 2);   // 2 MB
  float* b0   = (float*)carve(4 * HID * 4);
  float* bc   = (float*)carve(4 * HID * 4);
  short* hb[2];
  hb[0] = (short*)carve((long)NBATCH * HID * 2);
  hb[1] = (short*)carve((long)NBATCH * HID * 2);
  const size_t big_bytes = (long)T_STEPS * NBATCH * HID * 2;  // 134 MB
  bool big = ws_size >= off + big_bytes + 512;
  short* cb_all = nullptr; short* cb[2] = {nullptr, nullptr};
  if (big) cb_all = (short*)carve(big_bytes);
  else { cb[0] = (short*)carve((long)NBATCH * HID * 2); cb[1] = (short*)carve((long)NBATCH * HID * 2); }

  cast_kernel<<<5376, 256, 0, stream>>>(W_hh, W_fc, cvec, Whhb, Wfcb, hb[0]);
  bias_kernel<<<1024, 256, 0, stream>>>(W_ih, b_ih, b_hh, b_fc, b0, bc);
  wc_kernel<<<4096, 256, 0, stream>>>(W_ih, W_fc, Wc);

  for (int t = 0; t < T_STEPS; ++t) {
    const short* xh = hb[t & 1];
    short* hb_next = hb[(t + 1) & 1];
    const short* xc; long xc_rs;
    const float* cprev; long cprev_rs;
    const float* bias; int use_c;
    short* cb_next; long cbn_rs;
    if (t == 0) {
      use_c = 0; xc = xh; xc_rs = HID;
      cprev = cvec; cprev_rs = HID;
      bias = b0;
    } else {
      use_c = 1; bias = bc;
      cprev = cst + (long)(t - 1) * HID; cprev_rs = (long)T_STEPS * HID;
      if (big) { xc = cb_all + (long)(t - 1) * HID; xc_rs = (long)T_STEPS * HID; }
      else     { xc = cb[t & 1]; xc_rs = HID; }
    }
    if (big) { cb_next = cb_all + (long)t * HID; cbn_rs = (long)T_STEPS * HID; }
    else     { cb_next = cb[(t + 1) & 1]; cbn_rs = HID; }
    step_kernel<<<1024, 128, 0, stream>>>(t, use_c, xc, xc_rs, xh, Wc, Whhb, bias,
                                          cprev, cprev_rs, hst, cst,
                                          hb_next, cb_next, cbn_rs);
  }
  if (big) fc_kernel<short><<<4096, 256, 0, stream>>>((const short*)cb_all, Wfcb, b_fc, ost);
  else     fc_kernel<float><<<4096, 256, 0, stream>>>((const float*)cst, Wfcb, b_fc, ost);
}

// Round 2
// 7879.366 us; speedup vs baseline: 1.5098x; 1.5098x over previous
//
#include <hip/hip_runtime.h>

#define T_STEPS 256
#define NBATCH  256
#define HID     1024
#define KTOT    2048

typedef short bf16x8 __attribute__((ext_vector_type(8)));
typedef float f32x4  __attribute__((ext_vector_type(4)));

__device__ inline short cvt_bf16(float f) {
  unsigned u = __builtin_bit_cast(unsigned, f);
  u += 0x7fffu + ((u >> 16) & 1u);   // round-to-nearest-even
  return (short)(u >> 16);
}

__device__ inline float fast_sigmoid(float x) {
  return __builtin_amdgcn_rcpf(1.0f + __builtin_amdgcn_exp2f(-1.44269504f * x));
}
__device__ inline float fast_tanh(float x) {
  return 2.0f * __builtin_amdgcn_rcpf(1.0f + __builtin_amdgcn_exp2f(-2.88539008f * x)) - 1.0f;
}

// ---- K1: Whh -> Wbig right half (permuted rows); Wfc cast; x0 build -------
// Wbig row permutation: u' = ug*64 + g*16 + uu  <->  in_row = g*1024 + ug*16 + uu
__global__ void cast_kernel(const float* __restrict__ Whh,
                            const float* __restrict__ Wfc,
                            const float* __restrict__ cvec,
                            short* __restrict__ Wbig,
                            short* __restrict__ Wfcb,
                            short* __restrict__ x0) {
  long i = (long)blockIdx.x * blockDim.x + threadIdx.x;   // float4 quad index
  const long nWhh = 4096L * 1024 / 4;   // 1048576
  const long nWfc = 1024L * 1024 / 4;   // 262144
  const long nX0  = 256L * KTOT / 4;    // 131072
  if (i < nWhh) {
    int up = (int)(i >> 8);             // output row in Wbig
    int c4 = ((int)i & 255) * 4;
    int g = (up >> 4) & 3, ug = up >> 6, uu = up & 15;
    int in_row = g * 1024 + ug * 16 + uu;
    float4 v = *(const float4*)(Whh + (long)in_row * 1024 + c4);
    short4 o;
    o.x = cvt_bf16(v.x); o.y = cvt_bf16(v.y); o.z = cvt_bf16(v.z); o.w = cvt_bf16(v.w);
    *(short4*)(Wbig + (long)up * KTOT + 1024 + c4) = o;
  } else if (i < nWhh + nWfc) {
    long q = i - nWhh;
    float4 v = ((const float4*)Wfc)[q];
    short4 o;
    o.x = cvt_bf16(v.x); o.y = cvt_bf16(v.y); o.z = cvt_bf16(v.z); o.w = cvt_bf16(v.w);
    *(short4*)(Wfcb + q * 4) = o;
  } else if (i < nWhh + nWfc + nX0) {
    long q = i - nWhh - nWfc;
    int m = (int)(q >> 9);              // 512 quads per 2048-col row
    int c4 = ((int)q & 511) * 4;
    short4 o;
    if (c4 < 1024) {                    // c-part is zero at t=0 (i0 = 0 fold)
      o.x = o.y = o.z = o.w = 0;
    } else {
      float4 v = *(const float4*)(cvec + (long)m * 1024 + (c4 - 1024));
      o.x = cvt_bf16(v.x); o.y = cvt_bf16(v.y); o.z = cvt_bf16(v.z); o.w = cvt_bf16(v.w);
    }
    *(short4*)(x0 + (long)m * KTOT + c4) = o;
  }
}

// ---- K2: b0 = b_ih+b_hh ; bc = b0 + W_ih @ b_fc  (permuted to u') ---------
__global__ void bias_kernel(const float* __restrict__ W_ih,
                            const float* __restrict__ b_ih,
                            const float* __restrict__ b_hh,
                            const float* __restrict__ b_fc,
                            float* __restrict__ b0r, float* __restrict__ bcr) {
  int w = threadIdx.x >> 6, l = threadIdx.x & 63;
  int n = blockIdx.x * 4 + w;          // 4096 rows, 4 waves/block
  const float* row = W_ih + (long)n * HID;
  float s = 0.f;
  for (int i = l; i < HID; i += 64) s += row[i] * b_fc[i];
  #pragma unroll
  for (int off = 32; off; off >>= 1) s += __shfl_xor(s, off, 64);
  if (l == 0) {
    int g = n >> 10, uidx = n & 1023, ug = uidx >> 4, uu = uidx & 15;
    int up = ug * 64 + g * 16 + uu;
    float base = b_ih[n] + b_hh[n];
    b0r[up] = base;
    bcr[up] = base + s;
  }
}

// ---- K3: Wc = W_ih @ W_fc -> Wbig left half (permuted rows, bf16) ---------
__global__ void wc_kernel(const float* __restrict__ W_ih,
                          const float* __restrict__ W_fc,
                          short* __restrict__ Wbig) {
  int w = threadIdx.x >> 6, l = threadIdx.x & 63;
  int tile = blockIdx.x * 4 + w;       // 16384 tiles: 256 n-tiles x 64 k-tiles
  int nt = tile >> 6, kt = tile & 63;
  int lr = l & 15, lq = l >> 4;
  f32x4 acc = {0.f, 0.f, 0.f, 0.f};
  const float* arow = W_ih + (long)(nt * 16 + lr) * HID + lq * 8;
  const float* bcol = W_fc + (long)(lq * 8) * HID + kt * 16 + lr;
  for (int jc = 0; jc < HID; jc += 32) {
    float4 a0 = *(const float4*)(arow + jc);
    float4 a1 = *(const float4*)(arow + jc + 4);
    bf16x8 a;
    a[0]=cvt_bf16(a0.x); a[1]=cvt_bf16(a0.y); a[2]=cvt_bf16(a0.z); a[3]=cvt_bf16(a0.w);
    a[4]=cvt_bf16(a1.x); a[5]=cvt_bf16(a1.y); a[6]=cvt_bf16(a1.z); a[7]=cvt_bf16(a1.w);
    bf16x8 b;
    #pragma unroll
    for (int jj = 0; jj < 8; ++jj) b[jj] = cvt_bf16(bcol[(long)(jc + jj) * HID]);
    acc = __builtin_amdgcn_mfma_f32_16x16x32_bf16(a, b, acc, 0, 0, 0);
  }
  int k = kt * 16 + lr;
  // n = nt*16 + lq*4 + r ; gate g = nt>>6 ; unit-group ug = nt&63 ; uu = lq*4+r
  int g = nt >> 6, ug = nt & 63;
  #pragma unroll
  for (int r = 0; r < 4; ++r) {
    int up = ug * 64 + g * 16 + lq * 4 + r;
    Wbig[(long)up * KTOT + k] = cvt_bf16(acc[r]);
  }
}

// ---- per-step: [64m x 64 gate-cols] per block, split-K over 4 waves -------
__global__ __launch_bounds__(256, 1)
void step_kernel(int t,
                 const short* __restrict__ x,      // [256][2048] bf16 (c|h)
                 const short* __restrict__ Wbig,   // [4096][2048] bf16 permuted
                 const float* __restrict__ bias,   // [4096] permuted
                 const float* __restrict__ cprev,  // fp32, row-stride cprev_rs
                 long cprev_rs,
                 float* __restrict__ hst, float* __restrict__ cst,
                 short* __restrict__ xnext) {
  int tid = threadIdx.x;
  int w = tid >> 6, l = tid & 63, lr = l & 15, lq = l >> 4;
  int b = blockIdx.x;
  int ug = (b & 7) * 8 + ((b >> 3) & 7);   // XCD-contiguous weight stripes
  int mg = b >> 6;

  const short* abase = x    + (long)(mg * 64 + lr) * KTOT + w * 512 + lq * 8;
  const short* bbase = Wbig + (long)(ug * 64 + lr) * KTOT + w * 512 + lq * 8;

  f32x4 acc[4][4] = {};
  #pragma unroll 2
  for (int kk = 0; kk < 512; kk += 32) {
    bf16x8 af[4], bfr[4];
    #pragma unroll
    for (int i = 0; i < 4; ++i) {
      af[i]  = *(const bf16x8*)(abase + (long)i * 16 * KTOT + kk);
      bfr[i] = *(const bf16x8*)(bbase + (long)i * 16 * KTOT + kk);
    }
    #pragma unroll
    for (int mi = 0; mi < 4; ++mi)
      #pragma unroll
      for (int ui = 0; ui < 4; ++ui)
        acc[mi][ui] = __builtin_amdgcn_mfma_f32_16x16x32_bf16(af[mi], bfr[ui], acc[mi][ui], 0, 0, 0);
  }

  // split-K reduction: wave w owns m-subtile mi=w for the epilogue
  __shared__ f32x4 lds4[4 * 4 * 4 * 64];   // [wv][mi][ui][lane] = 64 KB
  #pragma unroll
  for (int mi = 0; mi < 4; ++mi)
    if (mi != w) {
      #pragma unroll
      for (int ui = 0; ui < 4; ++ui)
        lds4[((w * 4 + mi) * 4 + ui) * 64 + l] = acc[mi][ui];
    }
  __syncthreads();
  f32x4 red[4];
  #pragma unroll
  for (int ui = 0; ui < 4; ++ui) {
    red[ui] = acc[w][ui];
    #pragma unroll
    for (int wv = 0; wv < 4; ++wv)
      if (wv != w) red[ui] += lds4[((wv * 4 + w) * 4 + ui) * 64 + l];
  }

  // fused LSTM cell: gate quadruple is in-lane across ui
  int unit = ug * 16 + lr;
  float bi = bias[ug * 64 +  0 + lr];
  float bff= bias[ug * 64 + 16 + lr];
  float bg = bias[ug * 64 + 32 + lr];
  float bo = bias[ug * 64 + 48 + lr];
  #pragma unroll
  for (int r = 0; r < 4; ++r) {
    int m = mg * 64 + w * 16 + lq * 4 + r;
    float c_old = cprev[(long)m * cprev_rs + unit];
    float ig = fast_sigmoid(red[0][r] + bi);
    float fg = fast_sigmoid(red[1][r] + bff);
    float gg = fast_tanh(red[2][r] + bg);
    float og = fast_sigmoid(red[3][r] + bo);
    float cn = fg * c_old + ig * gg;
    float hn = og * fast_tanh(cn);
    long o = ((long)m * T_STEPS + t) * HID + unit;
    hst[o] = hn;
    cst[o] = cn;
    xnext[(long)m * KTOT + unit]        = cvt_bf16(cn);
    xnext[(long)m * KTOT + 1024 + unit] = cvt_bf16(hn);
  }
}

// ---- K4: outputs = c_states @ W_fc.T + b_fc  (A read fp32 from cst) -------
__global__ void fc_kernel(const float* __restrict__ A,      // [65536,1024] rows = b*256+t
                          const short* __restrict__ Bw,     // W_fc bf16 [1024,1024]
                          const float* __restrict__ b_fc,
                          float* __restrict__ out) {
  int w = threadIdx.x >> 6, l = threadIdx.x & 63;
  int wave = blockIdx.x * 4 + w;       // 16384 waves: 1024 m-tiles x 16 u-tiles
  int ut = wave & 15, mt = wave >> 4;
  int lr = l & 15, lq = l >> 4;
  f32x4 acc[4][4] = {};
  const float* arow[4]; const short* brow[4];
  #pragma unroll
  for (int i = 0; i < 4; ++i) {
    arow[i] = A  + (long)(mt * 64 + i * 16 + lr) * HID + lq * 8;
    brow[i] = Bw + (long)(ut * 64 + i * 16 + lr) * HID + lq * 8;
  }
  for (int kc = 0; kc < HID; kc += 32) {
    bf16x8 a[4], b[4];
    #pragma unroll
    for (int i = 0; i < 4; ++i) {
      float4 v0 = *(const float4*)(arow[i] + kc);
      float4 v1 = *(const float4*)(arow[i] + kc + 4);
      bf16x8 r;
      r[0]=cvt_bf16(v0.x); r[1]=cvt_bf16(v0.y); r[2]=cvt_bf16(v0.z); r[3]=cvt_bf16(v0.w);
      r[4]=cvt_bf16(v1.x); r[5]=cvt_bf16(v1.y); r[6]=cvt_bf16(v1.z); r[7]=cvt_bf16(v1.w);
      a[i] = r;
      b[i] = *(const bf16x8*)(brow[i] + kc);
    }
    #pragma unroll
    for (int mi = 0; mi < 4; ++mi)
      #pragma unroll
      for (int ui = 0; ui < 4; ++ui)
        acc[mi][ui] = __builtin_amdgcn_mfma_f32_16x16x32_bf16(a[mi], b[ui], acc[mi][ui], 0, 0, 0);
  }
  int u0 = ut * 64;
  #pragma unroll
  for (int ui = 0; ui < 4; ++ui) {
    float bf = b_fc[u0 + ui * 16 + lr];
    #pragma unroll
    for (int mi = 0; mi < 4; ++mi)
      #pragma unroll
      for (int r = 0; r < 4; ++r) {
        long mo = (long)mt * 64 + mi * 16 + lq * 4 + r;
        out[mo * HID + u0 + ui * 16 + lr] = acc[mi][ui][r] + bf;
      }
  }
}

// ---------------------------------------------------------------------------
extern "C" void kernel_launch(void* const* d_in, const int* in_sizes, int n_in,
                              void* d_out, int out_size, void* d_ws, size_t ws_size,
                              hipStream_t stream) {
  const float* cvec = (const float*)d_in[0];
  const float* W_ih = (const float*)d_in[1];
  const float* W_hh = (const float*)d_in[2];
  const float* b_ih = (const float*)d_in[3];
  const float* b_hh = (const float*)d_in[4];
  const float* W_fc = (const float*)d_in[5];
  const float* b_fc = (const float*)d_in[6];
  float* out = (float*)d_out;
  float* hst = out;
  float* cst = out + (long)NBATCH * T_STEPS * HID;
  float* ost = out + 2L * NBATCH * T_STEPS * HID;

  char* base = (char*)d_ws;
  size_t off = 0;
  auto carve = [&](size_t bytes) -> char* {
    char* r = base + off;
    off = (off + bytes + 255) & ~(size_t)255;
    return r;
  };
  short* Wbig = (short*)carve(4096L * KTOT * 2);      // 16 MB
  short* Wfcb = (short*)carve(1024L * 1024 * 2);      // 2 MB
  float* b0r  = (float*)carve(4096 * 4);
  float* bcr  = (float*)carve(4096 * 4);
  short* xb[2];
  xb[0] = (short*)carve((long)NBATCH * KTOT * 2);     // 1 MB
  xb[1] = (short*)carve((long)NBATCH * KTOT * 2);     // 1 MB

  cast_kernel<<<5632, 256, 0, stream>>>(W_hh, W_fc, cvec, Wbig, Wfcb, xb[0]);
  bias_kernel<<<1024, 256, 0, stream>>>(W_ih, b_ih, b_hh, b_fc, b0r, bcr);
  wc_kernel<<<4096, 256, 0, stream>>>(W_ih, W_fc, Wbig);

  for (int t = 0; t < T_STEPS; ++t) {
    const float* cprev = (t == 0) ? cvec : (cst + (long)(t - 1) * HID);
    long cprev_rs = (t == 0) ? (long)HID : (long)T_STEPS * HID;
    const float* bias = (t == 0) ? b0r : bcr;
    step_kernel<<<256, 256, 0, stream>>>(t, xb[t & 1], Wbig, bias,
                                         cprev, cprev_rs, hst, cst,
                                         xb[(t + 1) & 1]);
  }
  fc_kernel<<<4096, 256, 0, stream>>>(cst, Wfcb, b_fc, ost);
}